// Round 1
// baseline (1795.460 us; speedup 1.0000x reference)
//
#include <hip/hip_runtime.h>
#include <math.h>

// Problem constants (fixed by the harness setup)
#define NELEM 500000
#define NSAMP 16384
#define DIM   256
#define NH    8
#define HDIM  32

// ---------------- K0: segment bounds via binary search ----------------
__global__ void k0_bounds(const int* __restrict__ seg, int* __restrict__ bounds) {
    int i = blockIdx.x * blockDim.x + threadIdx.x;
    if (i > NSAMP) return;
    int lo = 0, hi = NELEM;
    while (lo < hi) {
        int mid = (lo + hi) >> 1;
        if (seg[mid] < i) lo = mid + 1; else hi = mid;
    }
    bounds[i] = lo;
}

// ---------------- K1: segment mean pooling (one wave per segment) ----------------
__global__ __launch_bounds__(64) void k1_pool(const float* __restrict__ E,
                                              const int* __restrict__ bounds,
                                              float* __restrict__ pooled) {
    int s = blockIdx.x, l = threadIdx.x;
    int start = bounds[s], end = bounds[s + 1];
    const float4* Ev = (const float4*)E;
    float4 a0 = make_float4(0.f, 0.f, 0.f, 0.f);
    float4 a1 = make_float4(0.f, 0.f, 0.f, 0.f);
    int e = start;
    for (; e + 1 < end; e += 2) {
        float4 v0 = Ev[(size_t)e * 64 + l];
        float4 v1 = Ev[(size_t)(e + 1) * 64 + l];
        a0.x += v0.x; a0.y += v0.y; a0.z += v0.z; a0.w += v0.w;
        a1.x += v1.x; a1.y += v1.y; a1.z += v1.z; a1.w += v1.w;
    }
    if (e < end) {
        float4 v0 = Ev[(size_t)e * 64 + l];
        a0.x += v0.x; a0.y += v0.y; a0.z += v0.z; a0.w += v0.w;
    }
    int cnt = end - start;
    float inv = 1.0f / (float)(cnt > 0 ? cnt : 1);
    float4 o;
    o.x = (a0.x + a1.x) * inv;
    o.y = (a0.y + a1.y) * inv;
    o.z = (a0.z + a1.z) * inv;
    o.w = (a0.w + a1.w) * inv;
    ((float4*)pooled)[(size_t)s * 64 + l] = o;
}

// ---------------- generic fp32 GEMM: C[M,256] = A[M,256] @ B[256,256] ----------------
// grid (M/64, 4), block 256. Tile 64x64, BK=16, micro 4x4.
__global__ __launch_bounds__(256) void gemm_256(const float* __restrict__ A,
                                                const float* __restrict__ B,
                                                float* __restrict__ C) {
    __shared__ float As[16][68];  // As[k][m] (transposed)
    __shared__ float Bs[16][68];  // Bs[k][n]
    int tx = threadIdx.x;
    int m0 = blockIdx.x * 64, n0 = blockIdx.y * 64;
    int ml = (tx >> 4) * 4, nl = (tx & 15) * 4;
    int lam = tx >> 2, lak = (tx & 3) * 4;       // A: row lam, 4 k's
    int lbk = tx >> 4, lbn = (tx & 15) * 4;      // B: row lbk, 4 n's
    float acc[4][4] = {};
    for (int k0 = 0; k0 < 256; k0 += 16) {
        float4 av = *(const float4*)&A[(size_t)(m0 + lam) * 256 + k0 + lak];
        float4 bv = *(const float4*)&B[(size_t)(k0 + lbk) * 256 + n0 + lbn];
        __syncthreads();
        As[lak + 0][lam] = av.x; As[lak + 1][lam] = av.y;
        As[lak + 2][lam] = av.z; As[lak + 3][lam] = av.w;
        *(float4*)&Bs[lbk][lbn] = bv;
        __syncthreads();
#pragma unroll
        for (int k = 0; k < 16; ++k) {
            float4 a4 = *(const float4*)&As[k][ml];
            float4 b4 = *(const float4*)&Bs[k][nl];
            float aa[4] = {a4.x, a4.y, a4.z, a4.w};
            float bb[4] = {b4.x, b4.y, b4.z, b4.w};
#pragma unroll
            for (int i = 0; i < 4; ++i)
#pragma unroll
                for (int j = 0; j < 4; ++j)
                    acc[i][j] = fmaf(aa[i], bb[j], acc[i][j]);
        }
    }
#pragma unroll
    for (int i = 0; i < 4; ++i) {
        float4 o = make_float4(acc[i][0], acc[i][1], acc[i][2], acc[i][3]);
        *(float4*)&C[(size_t)(m0 + ml + i) * 256 + n0 + nl] = o;
    }
}

// ---------------- K2b: t[s,h,i] = (1/sqrt(32)) * sum_d q[s,h*32+d] * Wk[i,h*32+d] ----------------
// grid (NSAMP/64, 8), block 256. Per-WG: 64 s-rows x 256 i, K=32.
__global__ __launch_bounds__(256) void k2b_t(const float* __restrict__ q,
                                             const float* __restrict__ Wk,
                                             float* __restrict__ t) {
    __shared__ float wkT[32][256];  // wkT[d][i] = Wk[i][h*32+d]
    __shared__ float qT[32][64];    // qT[d][ss] = q[s0+ss][h*32+d]
    int tx = threadIdx.x;
    int s0 = blockIdx.x * 64, h = blockIdx.y;
#pragma unroll
    for (int it = 0; it < 8; ++it) {
        int idx = tx + it * 256;             // 0..2047
        int i = idx >> 3, dq = (idx & 7) * 4;
        float4 v = *(const float4*)&Wk[(size_t)i * 256 + h * 32 + dq];
        wkT[dq + 0][i] = v.x; wkT[dq + 1][i] = v.y;
        wkT[dq + 2][i] = v.z; wkT[dq + 3][i] = v.w;
    }
#pragma unroll
    for (int it = 0; it < 2; ++it) {
        int idx = tx + it * 256;             // 0..511
        int ss = idx >> 3, dq = (idx & 7) * 4;
        float4 v = *(const float4*)&q[(size_t)(s0 + ss) * 256 + h * 32 + dq];
        qT[dq + 0][ss] = v.x; qT[dq + 1][ss] = v.y;
        qT[dq + 2][ss] = v.z; qT[dq + 3][ss] = v.w;
    }
    __syncthreads();
    int sl = (tx >> 4) * 4, i0 = (tx & 15) * 16;
    float acc[4][16] = {};
#pragma unroll 8
    for (int k = 0; k < 32; ++k) {
        float4 q4 = *(const float4*)&qT[k][sl];
        float4 w0 = *(const float4*)&wkT[k][i0];
        float4 w1 = *(const float4*)&wkT[k][i0 + 4];
        float4 w2 = *(const float4*)&wkT[k][i0 + 8];
        float4 w3 = *(const float4*)&wkT[k][i0 + 12];
        float qa[4] = {q4.x, q4.y, q4.z, q4.w};
        float wb[16] = {w0.x, w0.y, w0.z, w0.w, w1.x, w1.y, w1.z, w1.w,
                        w2.x, w2.y, w2.z, w2.w, w3.x, w3.y, w3.z, w3.w};
#pragma unroll
        for (int a = 0; a < 4; ++a)
#pragma unroll
            for (int b = 0; b < 16; ++b)
                acc[a][b] = fmaf(qa[a], wb[b], acc[a][b]);
    }
    const float scale = 0.17677669529663687f;  // 1/sqrt(32)
#pragma unroll
    for (int a = 0; a < 4; ++a)
#pragma unroll
        for (int bq = 0; bq < 4; ++bq) {
            float4 o = make_float4(acc[a][bq * 4 + 0] * scale, acc[a][bq * 4 + 1] * scale,
                                   acc[a][bq * 4 + 2] * scale, acc[a][bq * 4 + 3] * scale);
            *(float4*)&t[(size_t)(s0 + sl + a) * 2048 + h * 256 + i0 + bq * 4] = o;
        }
}

// ---------------- K3: per-segment online-softmax attention -> pw[s,h,i] ----------------
// One wave per segment. Lane l: head h=l>>3, i-chunk i0=(l&7)*32 (32 floats of pw in regs).
__global__ __launch_bounds__(64) void k3_attn(const float* __restrict__ E,
                                              const float* __restrict__ t,
                                              const int* __restrict__ bounds,
                                              float* __restrict__ pw) {
    __shared__ float ts[NH][260];  // +4 pad: spreads head rows across banks
    int s = blockIdx.x, l = threadIdx.x;
    const float4* tg = (const float4*)(t + (size_t)s * 2048);
#pragma unroll
    for (int j = 0; j < 8; ++j) {
        float4 v = tg[l + 64 * j];
        int fi = (l + 64 * j) * 4;           // flat float index
        *(float4*)&ts[fi >> 8][fi & 255] = v;
    }
    __syncthreads();
    int start = bounds[s], end = bounds[s + 1];
    int h = l >> 3;
    int i0 = (l & 7) * 32;
    const float* trow = &ts[h][i0];
    float tv[32];
#pragma unroll
    for (int j = 0; j < 8; ++j) {
        float4 w = *(const float4*)&trow[j * 4];
        tv[j * 4 + 0] = w.x; tv[j * 4 + 1] = w.y; tv[j * 4 + 2] = w.z; tv[j * 4 + 3] = w.w;
    }
    // pass 1: online max / denom
    float m = -INFINITY, d = 0.f;
    for (int e = start; e < end; ++e) {
        const float* er = E + (size_t)e * 256 + i0;
        float sc = 0.f;
#pragma unroll
        for (int j = 0; j < 8; ++j) {
            float4 v = *(const float4*)&er[j * 4];
            sc = fmaf(v.x, tv[j * 4 + 0], sc);
            sc = fmaf(v.y, tv[j * 4 + 1], sc);
            sc = fmaf(v.z, tv[j * 4 + 2], sc);
            sc = fmaf(v.w, tv[j * 4 + 3], sc);
        }
        sc += __shfl_xor(sc, 1, 64);
        sc += __shfl_xor(sc, 2, 64);
        sc += __shfl_xor(sc, 4, 64);
        float nm = fmaxf(m, sc);
        d = d * __expf(m - nm) + __expf(sc - nm);
        m = nm;
    }
    float rd = d > 0.f ? 1.0f / d : 0.f;
    // pass 2: probs * E accumulation (E re-read hits L1/L2)
    float4 acc[8];
#pragma unroll
    for (int j = 0; j < 8; ++j) acc[j] = make_float4(0.f, 0.f, 0.f, 0.f);
    for (int e = start; e < end; ++e) {
        const float* er = E + (size_t)e * 256 + i0;
        float4 v[8];
        float sc = 0.f;
#pragma unroll
        for (int j = 0; j < 8; ++j) {
            v[j] = *(const float4*)&er[j * 4];
            sc = fmaf(v[j].x, tv[j * 4 + 0], sc);
            sc = fmaf(v[j].y, tv[j * 4 + 1], sc);
            sc = fmaf(v[j].z, tv[j * 4 + 2], sc);
            sc = fmaf(v[j].w, tv[j * 4 + 3], sc);
        }
        sc += __shfl_xor(sc, 1, 64);
        sc += __shfl_xor(sc, 2, 64);
        sc += __shfl_xor(sc, 4, 64);
        float p = __expf(sc - m) * rd;
#pragma unroll
        for (int j = 0; j < 8; ++j) {
            acc[j].x = fmaf(p, v[j].x, acc[j].x);
            acc[j].y = fmaf(p, v[j].y, acc[j].y);
            acc[j].z = fmaf(p, v[j].z, acc[j].z);
            acc[j].w = fmaf(p, v[j].w, acc[j].w);
        }
    }
    float* o = pw + (size_t)s * 2048 + h * 256 + i0;
#pragma unroll
    for (int j = 0; j < 8; ++j) ((float4*)o)[j] = acc[j];
}

// ---------------- K4a: ps[s,h*32+d] = sum_k pw[s,h,k] * Wv[k,h*32+d] ----------------
// grid (NSAMP/64, 8), block 256. Micro: 8 s-rows x 1 d per thread, K=256 in BK=32 chunks.
__global__ __launch_bounds__(256) void k4a_ps(const float* __restrict__ pw,
                                              const float* __restrict__ Wv,
                                              float* __restrict__ ps) {
    __shared__ float at[32][68];  // at[k][ss]
    __shared__ float bt[32][36];  // bt[k][d]
    int tx = threadIdx.x;
    int s0 = blockIdx.x * 64, h = blockIdx.y;
    int dd = tx & 31, sl = (tx >> 5) * 8;
    float acc[8] = {};
    for (int k0 = 0; k0 < 256; k0 += 32) {
        __syncthreads();
#pragma unroll
        for (int it = 0; it < 2; ++it) {
            int idx = tx + it * 256;
            int ss = idx >> 3, kq = (idx & 7) * 4;
            float4 v = *(const float4*)&pw[(size_t)(s0 + ss) * 2048 + h * 256 + k0 + kq];
            at[kq + 0][ss] = v.x; at[kq + 1][ss] = v.y;
            at[kq + 2][ss] = v.z; at[kq + 3][ss] = v.w;
        }
        {
            int k = tx >> 3, dq = (tx & 7) * 4;
            float4 v = *(const float4*)&Wv[(size_t)(k0 + k) * 256 + h * 32 + dq];
            *(float4*)&bt[k][dq] = v;
        }
        __syncthreads();
#pragma unroll
        for (int k = 0; k < 32; ++k) {
            float b = bt[k][dd];
            float4 a0 = *(const float4*)&at[k][sl];
            float4 a1 = *(const float4*)&at[k][sl + 4];
            acc[0] = fmaf(a0.x, b, acc[0]); acc[1] = fmaf(a0.y, b, acc[1]);
            acc[2] = fmaf(a0.z, b, acc[2]); acc[3] = fmaf(a0.w, b, acc[3]);
            acc[4] = fmaf(a1.x, b, acc[4]); acc[5] = fmaf(a1.y, b, acc[5]);
            acc[6] = fmaf(a1.z, b, acc[6]); acc[7] = fmaf(a1.w, b, acc[7]);
        }
    }
#pragma unroll
    for (int j = 0; j < 8; ++j)
        ps[(size_t)(s0 + sl + j) * 256 + h * 32 + dd] = acc[j];
}

// ---------------- launch ----------------
// Workspace layout (floats):
//   pooled/ps : 0          (4,194,304)   -- ps reuses pooled (dead after gemm q)
//   q         : 4,194,304  (4,194,304)
//   t         : 8,388,608  (33,554,432)
//   pw        : 41,943,040 (33,554,432)
//   bounds    : 75,497,472 (16,385 ints)
// Total ~302 MB.
extern "C" void kernel_launch(void* const* d_in, const int* in_sizes, int n_in,
                              void* d_out, int out_size, void* d_ws, size_t ws_size,
                              hipStream_t stream) {
    const float* E  = (const float*)d_in[0];
    const int* seg  = (const int*)d_in[1];
    const float* Wq = (const float*)d_in[3];
    const float* Wk = (const float*)d_in[4];
    const float* Wv = (const float*)d_in[5];
    const float* Wo = (const float*)d_in[6];
    float* out = (float*)d_out;
    float* ws = (float*)d_ws;

    float* pooled = ws;
    float* q      = ws + 4194304;
    float* t      = ws + 8388608;
    float* pw     = ws + 41943040;
    int* bounds   = (int*)(ws + 75497472);
    float* ps     = pooled;

    k0_bounds<<<(NSAMP + 256) / 256, 256, 0, stream>>>(seg, bounds);
    k1_pool<<<NSAMP, 64, 0, stream>>>(E, bounds, pooled);
    gemm_256<<<dim3(NSAMP / 64, 4), 256, 0, stream>>>(pooled, Wq, q);
    k2b_t<<<dim3(NSAMP / 64, NH), 256, 0, stream>>>(q, Wk, t);
    k3_attn<<<NSAMP, 64, 0, stream>>>(E, t, bounds, pw);
    k4a_ps<<<dim3(NSAMP / 64, NH), 256, 0, stream>>>(pw, Wv, ps);
    gemm_256<<<dim3(NSAMP / 64, 4), 256, 0, stream>>>(ps, Wo, out);
}

// Round 2
// 1521.501 us; speedup vs baseline: 1.1801x; 1.1801x over previous
//
#include <hip/hip_runtime.h>
#include <math.h>

// Problem constants (fixed by the harness setup)
#define NELEM 500000
#define NSAMP 16384
#define DIM   256
#define NH    8
#define HDIM  32

// ---------------- K0: segment bounds via binary search ----------------
__global__ void k0_bounds(const int* __restrict__ seg, int* __restrict__ bounds) {
    int i = blockIdx.x * blockDim.x + threadIdx.x;
    if (i > NSAMP) return;
    int lo = 0, hi = NELEM;
    while (lo < hi) {
        int mid = (lo + hi) >> 1;
        if (seg[mid] < i) lo = mid + 1; else hi = mid;
    }
    bounds[i] = lo;
}

// ---------------- K1: segment mean pooling (4 segments per 256-block, wave each) ----------------
__global__ __launch_bounds__(256) void k1_pool(const float* __restrict__ E,
                                               const int* __restrict__ bounds,
                                               float* __restrict__ pooled) {
    int l = threadIdx.x & 63;
    int s = blockIdx.x * 4 + (threadIdx.x >> 6);
    int start = bounds[s], end = bounds[s + 1];
    const float4* Ev = (const float4*)E;
    float4 a0 = make_float4(0.f, 0.f, 0.f, 0.f);
    float4 a1 = make_float4(0.f, 0.f, 0.f, 0.f);
    float4 a2 = make_float4(0.f, 0.f, 0.f, 0.f);
    float4 a3 = make_float4(0.f, 0.f, 0.f, 0.f);
    int e = start;
    for (; e + 3 < end; e += 4) {
        float4 v0 = Ev[(size_t)(e + 0) * 64 + l];
        float4 v1 = Ev[(size_t)(e + 1) * 64 + l];
        float4 v2 = Ev[(size_t)(e + 2) * 64 + l];
        float4 v3 = Ev[(size_t)(e + 3) * 64 + l];
        a0.x += v0.x; a0.y += v0.y; a0.z += v0.z; a0.w += v0.w;
        a1.x += v1.x; a1.y += v1.y; a1.z += v1.z; a1.w += v1.w;
        a2.x += v2.x; a2.y += v2.y; a2.z += v2.z; a2.w += v2.w;
        a3.x += v3.x; a3.y += v3.y; a3.z += v3.z; a3.w += v3.w;
    }
    for (; e < end; ++e) {
        float4 v0 = Ev[(size_t)e * 64 + l];
        a0.x += v0.x; a0.y += v0.y; a0.z += v0.z; a0.w += v0.w;
    }
    int cnt = end - start;
    float inv = 1.0f / (float)(cnt > 0 ? cnt : 1);
    float4 o;
    o.x = (a0.x + a1.x + a2.x + a3.x) * inv;
    o.y = (a0.y + a1.y + a2.y + a3.y) * inv;
    o.z = (a0.z + a1.z + a2.z + a3.z) * inv;
    o.w = (a0.w + a1.w + a2.w + a3.w) * inv;
    ((float4*)pooled)[(size_t)s * 64 + l] = o;
}

// ---------------- generic fp32 GEMM: C[M,256] = A[M,256] @ B[256,256] ----------------
__global__ __launch_bounds__(256) void gemm_256(const float* __restrict__ A,
                                                const float* __restrict__ B,
                                                float* __restrict__ C) {
    __shared__ float As[16][68];  // As[k][m] (transposed)
    __shared__ float Bs[16][68];  // Bs[k][n]
    int tx = threadIdx.x;
    int m0 = blockIdx.x * 64, n0 = blockIdx.y * 64;
    int ml = (tx >> 4) * 4, nl = (tx & 15) * 4;
    int lam = tx >> 2, lak = (tx & 3) * 4;
    int lbk = tx >> 4, lbn = (tx & 15) * 4;
    float acc[4][4] = {};
    for (int k0 = 0; k0 < 256; k0 += 16) {
        float4 av = *(const float4*)&A[(size_t)(m0 + lam) * 256 + k0 + lak];
        float4 bv = *(const float4*)&B[(size_t)(k0 + lbk) * 256 + n0 + lbn];
        __syncthreads();
        As[lak + 0][lam] = av.x; As[lak + 1][lam] = av.y;
        As[lak + 2][lam] = av.z; As[lak + 3][lam] = av.w;
        *(float4*)&Bs[lbk][lbn] = bv;
        __syncthreads();
#pragma unroll
        for (int k = 0; k < 16; ++k) {
            float4 a4 = *(const float4*)&As[k][ml];
            float4 b4 = *(const float4*)&Bs[k][nl];
            float aa[4] = {a4.x, a4.y, a4.z, a4.w};
            float bb[4] = {b4.x, b4.y, b4.z, b4.w};
#pragma unroll
            for (int i = 0; i < 4; ++i)
#pragma unroll
                for (int j = 0; j < 4; ++j)
                    acc[i][j] = fmaf(aa[i], bb[j], acc[i][j]);
        }
    }
#pragma unroll
    for (int i = 0; i < 4; ++i) {
        float4 o = make_float4(acc[i][0], acc[i][1], acc[i][2], acc[i][3]);
        *(float4*)&C[(size_t)(m0 + ml + i) * 256 + n0 + nl] = o;
    }
}

// ---------------- K2b: t[s,h,i] = (1/sqrt(32)) * sum_d q[s,h*32+d] * Wk[i,h*32+d] ----------------
__global__ __launch_bounds__(256) void k2b_t(const float* __restrict__ q,
                                             const float* __restrict__ Wk,
                                             float* __restrict__ t) {
    __shared__ float wkT[32][256];
    __shared__ float qT[32][64];
    int tx = threadIdx.x;
    int s0 = blockIdx.x * 64, h = blockIdx.y;
#pragma unroll
    for (int it = 0; it < 8; ++it) {
        int idx = tx + it * 256;
        int i = idx >> 3, dq = (idx & 7) * 4;
        float4 v = *(const float4*)&Wk[(size_t)i * 256 + h * 32 + dq];
        wkT[dq + 0][i] = v.x; wkT[dq + 1][i] = v.y;
        wkT[dq + 2][i] = v.z; wkT[dq + 3][i] = v.w;
    }
#pragma unroll
    for (int it = 0; it < 2; ++it) {
        int idx = tx + it * 256;
        int ss = idx >> 3, dq = (idx & 7) * 4;
        float4 v = *(const float4*)&q[(size_t)(s0 + ss) * 256 + h * 32 + dq];
        qT[dq + 0][ss] = v.x; qT[dq + 1][ss] = v.y;
        qT[dq + 2][ss] = v.z; qT[dq + 3][ss] = v.w;
    }
    __syncthreads();
    int sl = (tx >> 4) * 4, i0 = (tx & 15) * 16;
    float acc[4][16] = {};
#pragma unroll 8
    for (int k = 0; k < 32; ++k) {
        float4 q4 = *(const float4*)&qT[k][sl];
        float4 w0 = *(const float4*)&wkT[k][i0];
        float4 w1 = *(const float4*)&wkT[k][i0 + 4];
        float4 w2 = *(const float4*)&wkT[k][i0 + 8];
        float4 w3 = *(const float4*)&wkT[k][i0 + 12];
        float qa[4] = {q4.x, q4.y, q4.z, q4.w};
        float wb[16] = {w0.x, w0.y, w0.z, w0.w, w1.x, w1.y, w1.z, w1.w,
                        w2.x, w2.y, w2.z, w2.w, w3.x, w3.y, w3.z, w3.w};
#pragma unroll
        for (int a = 0; a < 4; ++a)
#pragma unroll
            for (int b = 0; b < 16; ++b)
                acc[a][b] = fmaf(qa[a], wb[b], acc[a][b]);
    }
    const float scale = 0.17677669529663687f;  // 1/sqrt(32)
#pragma unroll
    for (int a = 0; a < 4; ++a)
#pragma unroll
        for (int bq = 0; bq < 4; ++bq) {
            float4 o = make_float4(acc[a][bq * 4 + 0] * scale, acc[a][bq * 4 + 1] * scale,
                                   acc[a][bq * 4 + 2] * scale, acc[a][bq * 4 + 3] * scale);
            *(float4*)&t[(size_t)(s0 + sl + a) * 2048 + h * 256 + i0 + bq * 4] = o;
        }
}

// ---------------- K3a: dense scores[e,h] = E[e] . t[seg[e],h]  ----------------
// Wave-collective: lane l -> head h=l>>3, dim chunk (l&7)*32. No cross-element deps.
#define K3A_CHUNK 16
__global__ __launch_bounds__(256) void k3a_scores(const float* __restrict__ E,
                                                  const float* __restrict__ t,
                                                  const int* __restrict__ seg,
                                                  float* __restrict__ scores) {
    int l = threadIdx.x & 63;
    int w = blockIdx.x * 4 + (threadIdx.x >> 6);
    int e0 = w * K3A_CHUNK;
    if (e0 >= NELEM) return;
    int e1 = e0 + K3A_CHUNK; if (e1 > NELEM) e1 = NELEM;
    int h = l >> 3;
    int c0 = (l & 7) * 32;
    bool leader = (l & 7) == 0;
    float tv[32];
    int scur = -1;
    for (int e = e0; e < e1; ++e) {
        int s = seg[e];                       // wave-uniform
        if (s != scur) {                      // uniform branch; ~1-2 reloads per chunk
            scur = s;
            const float* tg = t + (size_t)s * 2048 + l * 32;
#pragma unroll
            for (int j = 0; j < 8; ++j) {
                float4 v = *(const float4*)&tg[j * 4];
                tv[j * 4 + 0] = v.x; tv[j * 4 + 1] = v.y;
                tv[j * 4 + 2] = v.z; tv[j * 4 + 3] = v.w;
            }
        }
        const float* er = E + (size_t)e * 256 + c0;
        float p[4] = {0.f, 0.f, 0.f, 0.f};
#pragma unroll
        for (int j = 0; j < 8; ++j) {
            float4 v = *(const float4*)&er[j * 4];
            p[j & 3] = fmaf(v.x, tv[j * 4 + 0], p[j & 3]);
            p[j & 3] = fmaf(v.y, tv[j * 4 + 1], p[j & 3]);
            p[j & 3] = fmaf(v.z, tv[j * 4 + 2], p[j & 3]);
            p[j & 3] = fmaf(v.w, tv[j * 4 + 3], p[j & 3]);
        }
        float sc = (p[0] + p[1]) + (p[2] + p[3]);
        sc += __shfl_xor(sc, 1, 64);
        sc += __shfl_xor(sc, 2, 64);
        sc += __shfl_xor(sc, 4, 64);
        if (leader) scores[(size_t)e * 8 + h] = sc;
    }
}

// ---------------- K3b: per-segment max + denom (lane-parallel elements) ----------------
// md[s][0..7]=m, md[s][8..15]=1/denom
__global__ __launch_bounds__(256) void k3b_md(const float* __restrict__ scores,
                                              const int* __restrict__ bounds,
                                              float* __restrict__ md) {
    int l = threadIdx.x & 63;
    int s = blockIdx.x * 4 + (threadIdx.x >> 6);
    int start = bounds[s], end = bounds[s + 1];
    float m[8], d[8];
#pragma unroll
    for (int i = 0; i < 8; ++i) { m[i] = -INFINITY; d[i] = 0.f; }
    for (int base = start; base < end; base += 64) {
        int n = end - base; if (n > 64) n = 64;
        float sc[8];
        if (l < n) {
            const float4* sp = (const float4*)(scores + (size_t)(base + l) * 8);
            float4 va = sp[0], vb = sp[1];
            sc[0] = va.x; sc[1] = va.y; sc[2] = va.z; sc[3] = va.w;
            sc[4] = vb.x; sc[5] = vb.y; sc[6] = vb.z; sc[7] = vb.w;
        } else {
#pragma unroll
            for (int i = 0; i < 8; ++i) sc[i] = -INFINITY;
        }
        float cm[8];
#pragma unroll
        for (int i = 0; i < 8; ++i) cm[i] = sc[i];
#pragma unroll
        for (int msk = 1; msk < 64; msk <<= 1)
#pragma unroll
            for (int i = 0; i < 8; ++i)
                cm[i] = fmaxf(cm[i], __shfl_xor(cm[i], msk, 64));
        float ce[8];
#pragma unroll
        for (int i = 0; i < 8; ++i) ce[i] = (l < n) ? __expf(sc[i] - cm[i]) : 0.f;
#pragma unroll
        for (int msk = 1; msk < 64; msk <<= 1)
#pragma unroll
            for (int i = 0; i < 8; ++i)
                ce[i] += __shfl_xor(ce[i], msk, 64);
        // online merge
#pragma unroll
        for (int i = 0; i < 8; ++i) {
            float nm = fmaxf(m[i], cm[i]);
            d[i] = d[i] * __expf(m[i] - nm) + ce[i] * __expf(cm[i] - nm);
            m[i] = nm;
        }
    }
    if (l == 0) {
        float o[16];
#pragma unroll
        for (int i = 0; i < 8; ++i) { o[i] = m[i]; o[8 + i] = d[i] > 0.f ? 1.0f / d[i] : 0.f; }
#pragma unroll
        for (int j = 0; j < 4; ++j)
            *(float4*)&md[(size_t)s * 16 + j * 4] =
                make_float4(o[j * 4], o[j * 4 + 1], o[j * 4 + 2], o[j * 4 + 3]);
    }
}

// ---------------- K3b2: probs (in-place on scores) ----------------
__global__ __launch_bounds__(256) void k3b2_probs(float* __restrict__ scores,
                                                  const int* __restrict__ seg,
                                                  const float* __restrict__ md) {
    int idx = blockIdx.x * 256 + threadIdx.x;
    if (idx >= NELEM * NH) return;
    int e = idx >> 3, h = idx & 7;
    int s = seg[e];
    float m = md[(size_t)s * 16 + h];
    float rd = md[(size_t)s * 16 + 8 + h];
    scores[idx] = __expf(scores[idx] - m) * rd;
}

// ---------------- K3c: per-segment weighted pool. Lane l owns dims [4l,4l+4). ----------------
__global__ __launch_bounds__(256) void k3c_pool(const float* __restrict__ E,
                                                const float* __restrict__ probs,
                                                const int* __restrict__ bounds,
                                                float* __restrict__ pw) {
    int l = threadIdx.x & 63;
    int s = blockIdx.x * 4 + (threadIdx.x >> 6);
    int start = bounds[s], end = bounds[s + 1];
    float4 acc[8];
#pragma unroll
    for (int i = 0; i < 8; ++i) acc[i] = make_float4(0.f, 0.f, 0.f, 0.f);
    int e = start;
    for (; e + 1 < end; e += 2) {
        float4 ev0 = *(const float4*)&E[(size_t)(e + 0) * 256 + 4 * l];
        float4 ev1 = *(const float4*)&E[(size_t)(e + 1) * 256 + 4 * l];
        const float4* pr0 = (const float4*)(probs + (size_t)(e + 0) * 8);
        const float4* pr1 = (const float4*)(probs + (size_t)(e + 1) * 8);
        float4 pa0 = pr0[0], pb0 = pr0[1];
        float4 pa1 = pr1[0], pb1 = pr1[1];
        float p0[8] = {pa0.x, pa0.y, pa0.z, pa0.w, pb0.x, pb0.y, pb0.z, pb0.w};
        float p1[8] = {pa1.x, pa1.y, pa1.z, pa1.w, pb1.x, pb1.y, pb1.z, pb1.w};
#pragma unroll
        for (int i = 0; i < 8; ++i) {
            acc[i].x = fmaf(p0[i], ev0.x, acc[i].x);
            acc[i].y = fmaf(p0[i], ev0.y, acc[i].y);
            acc[i].z = fmaf(p0[i], ev0.z, acc[i].z);
            acc[i].w = fmaf(p0[i], ev0.w, acc[i].w);
        }
#pragma unroll
        for (int i = 0; i < 8; ++i) {
            acc[i].x = fmaf(p1[i], ev1.x, acc[i].x);
            acc[i].y = fmaf(p1[i], ev1.y, acc[i].y);
            acc[i].z = fmaf(p1[i], ev1.z, acc[i].z);
            acc[i].w = fmaf(p1[i], ev1.w, acc[i].w);
        }
    }
    if (e < end) {
        float4 ev0 = *(const float4*)&E[(size_t)e * 256 + 4 * l];
        const float4* pr0 = (const float4*)(probs + (size_t)e * 8);
        float4 pa0 = pr0[0], pb0 = pr0[1];
        float p0[8] = {pa0.x, pa0.y, pa0.z, pa0.w, pb0.x, pb0.y, pb0.z, pb0.w};
#pragma unroll
        for (int i = 0; i < 8; ++i) {
            acc[i].x = fmaf(p0[i], ev0.x, acc[i].x);
            acc[i].y = fmaf(p0[i], ev0.y, acc[i].y);
            acc[i].z = fmaf(p0[i], ev0.z, acc[i].z);
            acc[i].w = fmaf(p0[i], ev0.w, acc[i].w);
        }
    }
#pragma unroll
    for (int h = 0; h < 8; ++h)
        *(float4*)&pw[(size_t)s * 2048 + h * 256 + 4 * l] = acc[h];
}

// ---------------- K4a: ps[s,h*32+d] = sum_k pw[s,h,k] * Wv[k,h*32+d] ----------------
__global__ __launch_bounds__(256) void k4a_ps(const float* __restrict__ pw,
                                              const float* __restrict__ Wv,
                                              float* __restrict__ ps) {
    __shared__ float at[32][68];
    __shared__ float bt[32][36];
    int tx = threadIdx.x;
    int s0 = blockIdx.x * 64, h = blockIdx.y;
    int dd = tx & 31, sl = (tx >> 5) * 8;
    float acc[8] = {};
    for (int k0 = 0; k0 < 256; k0 += 32) {
        __syncthreads();
#pragma unroll
        for (int it = 0; it < 2; ++it) {
            int idx = tx + it * 256;
            int ss = idx >> 3, kq = (idx & 7) * 4;
            float4 v = *(const float4*)&pw[(size_t)(s0 + ss) * 2048 + h * 256 + k0 + kq];
            at[kq + 0][ss] = v.x; at[kq + 1][ss] = v.y;
            at[kq + 2][ss] = v.z; at[kq + 3][ss] = v.w;
        }
        {
            int k = tx >> 3, dq = (tx & 7) * 4;
            float4 v = *(const float4*)&Wv[(size_t)(k0 + k) * 256 + h * 32 + dq];
            *(float4*)&bt[k][dq] = v;
        }
        __syncthreads();
#pragma unroll
        for (int k = 0; k < 32; ++k) {
            float b = bt[k][dd];
            float4 a0 = *(const float4*)&at[k][sl];
            float4 a1 = *(const float4*)&at[k][sl + 4];
            acc[0] = fmaf(a0.x, b, acc[0]); acc[1] = fmaf(a0.y, b, acc[1]);
            acc[2] = fmaf(a0.z, b, acc[2]); acc[3] = fmaf(a0.w, b, acc[3]);
            acc[4] = fmaf(a1.x, b, acc[4]); acc[5] = fmaf(a1.y, b, acc[5]);
            acc[6] = fmaf(a1.z, b, acc[6]); acc[7] = fmaf(a1.w, b, acc[7]);
        }
    }
#pragma unroll
    for (int j = 0; j < 8; ++j)
        ps[(size_t)(s0 + sl + j) * 256 + h * 32 + dd] = acc[j];
}

// ---------------- launch ----------------
// Workspace layout (floats):
//   pooled/ps     : 0           (4,194,304)
//   q             : 4,194,304   (4,194,304)
//   t / pw        : 8,388,608   (33,554,432)  -- t dead after k3a; pw reuses it
//   scores/probs  : 41,943,040  (4,000,000)   -- probs computed in-place
//   md            : 45,943,040  (262,144)
//   bounds        : 46,205,184  (16,385 ints)
// Total ~185 MB.
extern "C" void kernel_launch(void* const* d_in, const int* in_sizes, int n_in,
                              void* d_out, int out_size, void* d_ws, size_t ws_size,
                              hipStream_t stream) {
    const float* E  = (const float*)d_in[0];
    const int* seg  = (const int*)d_in[1];
    const float* Wq = (const float*)d_in[3];
    const float* Wk = (const float*)d_in[4];
    const float* Wv = (const float*)d_in[5];
    const float* Wo = (const float*)d_in[6];
    float* out = (float*)d_out;
    float* ws = (float*)d_ws;

    float* pooled = ws;
    float* q      = ws + 4194304;
    float* t      = ws + 8388608;   // also pw
    float* scores = ws + 41943040;  // also probs
    float* md     = ws + 45943040;
    int* bounds   = (int*)(ws + 46205184);
    float* pw     = t;
    float* ps     = pooled;

    k0_bounds<<<(NSAMP + 256) / 256, 256, 0, stream>>>(seg, bounds);
    k1_pool<<<NSAMP / 4, 256, 0, stream>>>(E, bounds, pooled);
    gemm_256<<<dim3(NSAMP / 64, 4), 256, 0, stream>>>(pooled, Wq, q);
    k2b_t<<<dim3(NSAMP / 64, NH), 256, 0, stream>>>(q, Wk, t);
    int k3a_waves = (NELEM + K3A_CHUNK - 1) / K3A_CHUNK;
    k3a_scores<<<(k3a_waves + 3) / 4, 256, 0, stream>>>(E, t, seg, scores);
    k3b_md<<<NSAMP / 4, 256, 0, stream>>>(scores, bounds, md);
    k3b2_probs<<<(NELEM * NH + 255) / 256, 256, 0, stream>>>(scores, seg, md);
    k3c_pool<<<NSAMP / 4, 256, 0, stream>>>(E, scores, bounds, pw);
    k4a_ps<<<dim3(NSAMP / 64, NH), 256, 0, stream>>>(pw, Wv, ps);
    gemm_256<<<dim3(NSAMP / 64, 4), 256, 0, stream>>>(ps, Wo, out);
}

// Round 3
// 1388.169 us; speedup vs baseline: 1.2934x; 1.0960x over previous
//
#include <hip/hip_runtime.h>
#include <math.h>

// Problem constants (fixed by the harness setup)
#define NELEM 500000
#define NSAMP 16384
#define DIM   256
#define NH    8
#define HDIM  32

// ---------------- K0: segment bounds via binary search ----------------
__global__ void k0_bounds(const int* __restrict__ seg, int* __restrict__ bounds) {
    int i = blockIdx.x * blockDim.x + threadIdx.x;
    if (i > NSAMP) return;
    int lo = 0, hi = NELEM;
    while (lo < hi) {
        int mid = (lo + hi) >> 1;
        if (seg[mid] < i) lo = mid + 1; else hi = mid;
    }
    bounds[i] = lo;
}

// ---------------- K1: segment mean pooling (4 segments per 256-block, wave each) ----------------
__global__ __launch_bounds__(256) void k1_pool(const float* __restrict__ E,
                                               const int* __restrict__ bounds,
                                               float* __restrict__ pooled) {
    int l = threadIdx.x & 63;
    int s = blockIdx.x * 4 + (threadIdx.x >> 6);
    int start = bounds[s], end = bounds[s + 1];
    const float4* Ev = (const float4*)E;
    float4 a0 = make_float4(0.f, 0.f, 0.f, 0.f);
    float4 a1 = make_float4(0.f, 0.f, 0.f, 0.f);
    float4 a2 = make_float4(0.f, 0.f, 0.f, 0.f);
    float4 a3 = make_float4(0.f, 0.f, 0.f, 0.f);
    int e = start;
    for (; e + 3 < end; e += 4) {
        float4 v0 = Ev[(size_t)(e + 0) * 64 + l];
        float4 v1 = Ev[(size_t)(e + 1) * 64 + l];
        float4 v2 = Ev[(size_t)(e + 2) * 64 + l];
        float4 v3 = Ev[(size_t)(e + 3) * 64 + l];
        a0.x += v0.x; a0.y += v0.y; a0.z += v0.z; a0.w += v0.w;
        a1.x += v1.x; a1.y += v1.y; a1.z += v1.z; a1.w += v1.w;
        a2.x += v2.x; a2.y += v2.y; a2.z += v2.z; a2.w += v2.w;
        a3.x += v3.x; a3.y += v3.y; a3.z += v3.z; a3.w += v3.w;
    }
    for (; e < end; ++e) {
        float4 v0 = Ev[(size_t)e * 64 + l];
        a0.x += v0.x; a0.y += v0.y; a0.z += v0.z; a0.w += v0.w;
    }
    int cnt = end - start;
    float inv = 1.0f / (float)(cnt > 0 ? cnt : 1);
    float4 o;
    o.x = (a0.x + a1.x + a2.x + a3.x) * inv;
    o.y = (a0.y + a1.y + a2.y + a3.y) * inv;
    o.z = (a0.z + a1.z + a2.z + a3.z) * inv;
    o.w = (a0.w + a1.w + a2.w + a3.w) * inv;
    ((float4*)pooled)[(size_t)s * 64 + l] = o;
}

// ---------------- generic fp32 GEMM: C[M,256] = A[M,256] @ B[256,256] ----------------
__global__ __launch_bounds__(256) void gemm_256(const float* __restrict__ A,
                                                const float* __restrict__ B,
                                                float* __restrict__ C) {
    __shared__ float As[16][68];  // As[k][m] (transposed)
    __shared__ float Bs[16][68];  // Bs[k][n]
    int tx = threadIdx.x;
    int m0 = blockIdx.x * 64, n0 = blockIdx.y * 64;
    int ml = (tx >> 4) * 4, nl = (tx & 15) * 4;
    int lam = tx >> 2, lak = (tx & 3) * 4;
    int lbk = tx >> 4, lbn = (tx & 15) * 4;
    float acc[4][4] = {};
    for (int k0 = 0; k0 < 256; k0 += 16) {
        float4 av = *(const float4*)&A[(size_t)(m0 + lam) * 256 + k0 + lak];
        float4 bv = *(const float4*)&B[(size_t)(k0 + lbk) * 256 + n0 + lbn];
        __syncthreads();
        As[lak + 0][lam] = av.x; As[lak + 1][lam] = av.y;
        As[lak + 2][lam] = av.z; As[lak + 3][lam] = av.w;
        *(float4*)&Bs[lbk][lbn] = bv;
        __syncthreads();
#pragma unroll
        for (int k = 0; k < 16; ++k) {
            float4 a4 = *(const float4*)&As[k][ml];
            float4 b4 = *(const float4*)&Bs[k][nl];
            float aa[4] = {a4.x, a4.y, a4.z, a4.w};
            float bb[4] = {b4.x, b4.y, b4.z, b4.w};
#pragma unroll
            for (int i = 0; i < 4; ++i)
#pragma unroll
                for (int j = 0; j < 4; ++j)
                    acc[i][j] = fmaf(aa[i], bb[j], acc[i][j]);
        }
    }
#pragma unroll
    for (int i = 0; i < 4; ++i) {
        float4 o = make_float4(acc[i][0], acc[i][1], acc[i][2], acc[i][3]);
        *(float4*)&C[(size_t)(m0 + ml + i) * 256 + n0 + nl] = o;
    }
}

// ---------------- K2b: t[s,h,i] = (1/sqrt(32)) * sum_d q[s,h*32+d] * Wk[i,h*32+d] ----------------
__global__ __launch_bounds__(256) void k2b_t(const float* __restrict__ q,
                                             const float* __restrict__ Wk,
                                             float* __restrict__ t) {
    __shared__ float wkT[32][256];
    __shared__ float qT[32][64];
    int tx = threadIdx.x;
    int s0 = blockIdx.x * 64, h = blockIdx.y;
#pragma unroll
    for (int it = 0; it < 8; ++it) {
        int idx = tx + it * 256;
        int i = idx >> 3, dq = (idx & 7) * 4;
        float4 v = *(const float4*)&Wk[(size_t)i * 256 + h * 32 + dq];
        wkT[dq + 0][i] = v.x; wkT[dq + 1][i] = v.y;
        wkT[dq + 2][i] = v.z; wkT[dq + 3][i] = v.w;
    }
#pragma unroll
    for (int it = 0; it < 2; ++it) {
        int idx = tx + it * 256;
        int ss = idx >> 3, dq = (idx & 7) * 4;
        float4 v = *(const float4*)&q[(size_t)(s0 + ss) * 256 + h * 32 + dq];
        qT[dq + 0][ss] = v.x; qT[dq + 1][ss] = v.y;
        qT[dq + 2][ss] = v.z; qT[dq + 3][ss] = v.w;
    }
    __syncthreads();
    int sl = (tx >> 4) * 4, i0 = (tx & 15) * 16;
    float acc[4][16] = {};
#pragma unroll 8
    for (int k = 0; k < 32; ++k) {
        float4 q4 = *(const float4*)&qT[k][sl];
        float4 w0 = *(const float4*)&wkT[k][i0];
        float4 w1 = *(const float4*)&wkT[k][i0 + 4];
        float4 w2 = *(const float4*)&wkT[k][i0 + 8];
        float4 w3 = *(const float4*)&wkT[k][i0 + 12];
        float qa[4] = {q4.x, q4.y, q4.z, q4.w};
        float wb[16] = {w0.x, w0.y, w0.z, w0.w, w1.x, w1.y, w1.z, w1.w,
                        w2.x, w2.y, w2.z, w2.w, w3.x, w3.y, w3.z, w3.w};
#pragma unroll
        for (int a = 0; a < 4; ++a)
#pragma unroll
            for (int b = 0; b < 16; ++b)
                acc[a][b] = fmaf(qa[a], wb[b], acc[a][b]);
    }
    const float scale = 0.17677669529663687f;  // 1/sqrt(32)
#pragma unroll
    for (int a = 0; a < 4; ++a)
#pragma unroll
        for (int bq = 0; bq < 4; ++bq) {
            float4 o = make_float4(acc[a][bq * 4 + 0] * scale, acc[a][bq * 4 + 1] * scale,
                                   acc[a][bq * 4 + 2] * scale, acc[a][bq * 4 + 3] * scale);
            *(float4*)&t[(size_t)(s0 + sl + a) * 2048 + h * 256 + i0 + bq * 4] = o;
        }
}

// ---------------- K3: flash-style fused scores+softmax+pool, one wave per segment ----------
// Lane l: head h=l>>3, dim chunk c0=(l&7)*32. After the 3 xor-shuffles ALL 8 lanes of a
// head group hold the full score, so online softmax state (m,d) and the weighted-pool
// accumulator live entirely in registers. E is read ONCE. 2-deep row prefetch for MLP.
__global__ __launch_bounds__(256) void k3_flash(const float* __restrict__ E,
                                                const float* __restrict__ t,
                                                const int* __restrict__ bounds,
                                                float* __restrict__ pw) {
    int l = threadIdx.x & 63;
    int s = blockIdx.x * 4 + (threadIdx.x >> 6);
    int start = bounds[s], end = bounds[s + 1];
    int h = l >> 3;
    int c0 = (l & 7) * 32;
    float* o = pw + (size_t)s * 2048 + h * 256 + c0;
    if (start >= end) {
        float4 z = make_float4(0.f, 0.f, 0.f, 0.f);
#pragma unroll
        for (int j = 0; j < 8; ++j) ((float4*)o)[j] = z;
        return;
    }
    // t fragment for this (head, chunk): 32 floats
    const float* tg = t + (size_t)s * 2048 + h * 256 + c0;
    float tv[32];
#pragma unroll
    for (int j = 0; j < 8; ++j) {
        float4 v = *(const float4*)&tg[j * 4];
        tv[j * 4 + 0] = v.x; tv[j * 4 + 1] = v.y;
        tv[j * 4 + 2] = v.z; tv[j * 4 + 3] = v.w;
    }
    float m = -INFINITY, d = 0.f;
    float4 acc[8];
#pragma unroll
    for (int j = 0; j < 8; ++j) acc[j] = make_float4(0.f, 0.f, 0.f, 0.f);
    float4 cur[8], nxt[8];
    {
        const float* er = E + (size_t)start * 256 + c0;
#pragma unroll
        for (int j = 0; j < 8; ++j) cur[j] = *(const float4*)&er[j * 4];
    }
    for (int e = start; e < end; ++e) {
        if (e + 1 < end) {  // wave-uniform branch; prefetch next row while computing cur
            const float* ern = E + (size_t)(e + 1) * 256 + c0;
#pragma unroll
            for (int j = 0; j < 8; ++j) nxt[j] = *(const float4*)&ern[j * 4];
        }
        float p0 = 0.f, p1 = 0.f, p2 = 0.f, p3 = 0.f;
#pragma unroll
        for (int j = 0; j < 8; j += 4) {
            p0 = fmaf(cur[j].x, tv[j * 4 + 0], p0);
            p0 = fmaf(cur[j].y, tv[j * 4 + 1], p0);
            p0 = fmaf(cur[j].z, tv[j * 4 + 2], p0);
            p0 = fmaf(cur[j].w, tv[j * 4 + 3], p0);
            p1 = fmaf(cur[j + 1].x, tv[j * 4 + 4], p1);
            p1 = fmaf(cur[j + 1].y, tv[j * 4 + 5], p1);
            p1 = fmaf(cur[j + 1].z, tv[j * 4 + 6], p1);
            p1 = fmaf(cur[j + 1].w, tv[j * 4 + 7], p1);
            p2 = fmaf(cur[j + 2].x, tv[j * 4 + 8], p2);
            p2 = fmaf(cur[j + 2].y, tv[j * 4 + 9], p2);
            p2 = fmaf(cur[j + 2].z, tv[j * 4 + 10], p2);
            p2 = fmaf(cur[j + 2].w, tv[j * 4 + 11], p2);
            p3 = fmaf(cur[j + 3].x, tv[j * 4 + 12], p3);
            p3 = fmaf(cur[j + 3].y, tv[j * 4 + 13], p3);
            p3 = fmaf(cur[j + 3].z, tv[j * 4 + 14], p3);
            p3 = fmaf(cur[j + 3].w, tv[j * 4 + 15], p3);
        }
        float sc = (p0 + p1) + (p2 + p3);
        sc += __shfl_xor(sc, 1, 64);
        sc += __shfl_xor(sc, 2, 64);
        sc += __shfl_xor(sc, 4, 64);
        float nm = fmaxf(m, sc);
        float al = __expf(m - nm);   // 0 on first element (m = -inf)
        float p  = __expf(sc - nm);
        d = d * al + p;
        m = nm;
#pragma unroll
        for (int j = 0; j < 8; ++j) {
            acc[j].x = fmaf(acc[j].x, al, p * cur[j].x);
            acc[j].y = fmaf(acc[j].y, al, p * cur[j].y);
            acc[j].z = fmaf(acc[j].z, al, p * cur[j].z);
            acc[j].w = fmaf(acc[j].w, al, p * cur[j].w);
        }
#pragma unroll
        for (int j = 0; j < 8; ++j) cur[j] = nxt[j];
    }
    float rd = 1.0f / d;
#pragma unroll
    for (int j = 0; j < 8; ++j) {
        float4 v = make_float4(acc[j].x * rd, acc[j].y * rd, acc[j].z * rd, acc[j].w * rd);
        ((float4*)o)[j] = v;
    }
}

// ---------------- K4a: ps[s,h*32+d] = sum_k pw[s,h,k] * Wv[k,h*32+d] ----------------
__global__ __launch_bounds__(256) void k4a_ps(const float* __restrict__ pw,
                                              const float* __restrict__ Wv,
                                              float* __restrict__ ps) {
    __shared__ float at[32][68];
    __shared__ float bt[32][36];
    int tx = threadIdx.x;
    int s0 = blockIdx.x * 64, h = blockIdx.y;
    int dd = tx & 31, sl = (tx >> 5) * 8;
    float acc[8] = {};
    for (int k0 = 0; k0 < 256; k0 += 32) {
        __syncthreads();
#pragma unroll
        for (int it = 0; it < 2; ++it) {
            int idx = tx + it * 256;
            int ss = idx >> 3, kq = (idx & 7) * 4;
            float4 v = *(const float4*)&pw[(size_t)(s0 + ss) * 2048 + h * 256 + k0 + kq];
            at[kq + 0][ss] = v.x; at[kq + 1][ss] = v.y;
            at[kq + 2][ss] = v.z; at[kq + 3][ss] = v.w;
        }
        {
            int k = tx >> 3, dq = (tx & 7) * 4;
            float4 v = *(const float4*)&Wv[(size_t)(k0 + k) * 256 + h * 32 + dq];
            *(float4*)&bt[k][dq] = v;
        }
        __syncthreads();
#pragma unroll
        for (int k = 0; k < 32; ++k) {
            float b = bt[k][dd];
            float4 a0 = *(const float4*)&at[k][sl];
            float4 a1 = *(const float4*)&at[k][sl + 4];
            acc[0] = fmaf(a0.x, b, acc[0]); acc[1] = fmaf(a0.y, b, acc[1]);
            acc[2] = fmaf(a0.z, b, acc[2]); acc[3] = fmaf(a0.w, b, acc[3]);
            acc[4] = fmaf(a1.x, b, acc[4]); acc[5] = fmaf(a1.y, b, acc[5]);
            acc[6] = fmaf(a1.z, b, acc[6]); acc[7] = fmaf(a1.w, b, acc[7]);
        }
    }
#pragma unroll
    for (int j = 0; j < 8; ++j)
        ps[(size_t)(s0 + sl + j) * 256 + h * 32 + dd] = acc[j];
}

// ---------------- launch ----------------
// Workspace layout (floats):
//   pooled/ps : 0          (4,194,304)   -- ps reuses pooled (dead after gemm q)
//   q         : 4,194,304  (4,194,304)
//   t         : 8,388,608  (33,554,432)
//   pw        : 41,943,040 (33,554,432)  -- cannot alias t (k3 reads t while writing pw)
//   bounds    : 75,497,472 (16,385 ints)
// Total ~302 MB (same as R0 layout, known to fit).
extern "C" void kernel_launch(void* const* d_in, const int* in_sizes, int n_in,
                              void* d_out, int out_size, void* d_ws, size_t ws_size,
                              hipStream_t stream) {
    const float* E  = (const float*)d_in[0];
    const int* seg  = (const int*)d_in[1];
    const float* Wq = (const float*)d_in[3];
    const float* Wk = (const float*)d_in[4];
    const float* Wv = (const float*)d_in[5];
    const float* Wo = (const float*)d_in[6];
    float* out = (float*)d_out;
    float* ws = (float*)d_ws;

    float* pooled = ws;
    float* q      = ws + 4194304;
    float* t      = ws + 8388608;
    float* pw     = ws + 41943040;
    int* bounds   = (int*)(ws + 75497472);
    float* ps     = pooled;

    k0_bounds<<<(NSAMP + 256) / 256, 256, 0, stream>>>(seg, bounds);
    k1_pool<<<NSAMP / 4, 256, 0, stream>>>(E, bounds, pooled);
    gemm_256<<<dim3(NSAMP / 64, 4), 256, 0, stream>>>(pooled, Wq, q);
    k2b_t<<<dim3(NSAMP / 64, NH), 256, 0, stream>>>(q, Wk, t);
    k3_flash<<<NSAMP / 4, 256, 0, stream>>>(E, t, bounds, pw);
    k4a_ps<<<dim3(NSAMP / 64, NH), 256, 0, stream>>>(pw, Wv, ps);
    gemm_256<<<dim3(NSAMP / 64, 4), 256, 0, stream>>>(ps, Wo, out);
}